// Round 7
// baseline (430.045 us; speedup 1.0000x reference)
//
#include <hip/hip_runtime.h>

#define TB      64      // samples per block (== wavefront; lane = sample)
#define THREADS 1024    // 16 waves -> 4 waves/SIMD
#define NWAVE   16
#define EMB     64
#define UFEAT   21
#define IFEAT   39
#define KXU     85      // EMB + UFEAT
#define KXI     103     // EMB + IFEAT
#define HW      128     // 2*EMB
// float strides: rows 16B-aligned (S%4==0) and S/4 odd -> ds_read_b128 conflict-free
#define XU_S    92
#define XI_S    108
#define H_S     132

// 8 outputs per wave over relu'd input x (K wide), k-tiled by 16:
// x tile -> 4x ds_read_b128 into VGPRs; W rows walked CONTIGUOUSLY (s_load_dwordx8+)
template<int K, int KT>
__device__ __forceinline__ void layer_tiled8(const float* __restrict__ x, int o0,
                                             const float* __restrict__ W,
                                             const float* __restrict__ b,
                                             float acc[8])
{
    // bias + raw-embedding residual (x[0..63] = raw embedding, residual is NOT relu'd)
    #pragma unroll
    for (int j = 0; j < 8; ++j) acc[j] = b[o0 + j] + x[o0 + j];

    #pragma unroll 2
    for (int t = 0; t < KT; ++t) {
        const int k0 = t * 16;
        float xv[16];
        #pragma unroll
        for (int q = 0; q < 4; ++q) {
            const float4 v = *reinterpret_cast<const float4*>(x + k0 + q * 4);
            xv[q * 4 + 0] = fmaxf(v.x, 0.f); xv[q * 4 + 1] = fmaxf(v.y, 0.f);
            xv[q * 4 + 2] = fmaxf(v.z, 0.f); xv[q * 4 + 3] = fmaxf(v.w, 0.f);
        }
        #pragma unroll
        for (int j = 0; j < 8; ++j) {
            const float* Wr = W + (o0 + j) * K + k0;   // contiguous 64B run, uniform
            #pragma unroll
            for (int kk = 0; kk < 16; ++kk)
                acc[j] = fmaf(xv[kk], Wr[kk], acc[j]);
        }
    }
    // tail k = KT*16 .. K-1  (5 for user, 7 for item)
    #pragma unroll
    for (int k = KT * 16; k < K; ++k) {
        const float a = fmaxf(x[k], 0.f);
        #pragma unroll
        for (int j = 0; j < 8; ++j)
            acc[j] = fmaf(a, W[(o0 + j) * K + k], acc[j]);
    }
}

__global__ __launch_bounds__(THREADS, 4)
void rec_fused(const int*   __restrict__ user_id,  const int*   __restrict__ item_id,
               const float* __restrict__ user_feat, const float* __restrict__ item_feat,
               const float* __restrict__ user_emb,  const float* __restrict__ item_emb,
               const float* __restrict__ W_uf, const float* __restrict__ b_uf,
               const float* __restrict__ W_if, const float* __restrict__ b_if,
               const float* __restrict__ W1,  const float* __restrict__ b1,
               const float* __restrict__ W2,  const float* __restrict__ b2,
               float* __restrict__ out)
{
    // H (64*132 floats) aliases the X staging region (64*(92+108) floats);
    // H is written only after the barrier that ends all X reads.
    __shared__ float smem[TB * XU_S + TB * XI_S];   // 51200 B
    __shared__ float sOut[NWAVE][TB];               // 4096 B -> 55296 B total

    const int t  = threadIdx.x;
    const int s0 = blockIdx.x * TB;
    float* sXU = smem;                 // row stride XU_S
    float* sXI = smem + TB * XU_S;     // row stride XI_S

    // ---- stage embeddings: one float4 per table per thread; user+item issued
    // back-to-back so their HBM latencies overlap ----
    {
        const int r = t >> 4, c = (t & 15) << 2;
        const int uid = user_id[s0 + r];
        const int iid = item_id[s0 + r];
        const float4 u = *reinterpret_cast<const float4*>(user_emb + uid * EMB + c);
        const float4 v = *reinterpret_cast<const float4*>(item_emb + iid * EMB + c);
        *reinterpret_cast<float4*>(sXU + r * XU_S + c) = u;   // rows 16B-aligned
        *reinterpret_cast<float4*>(sXI + r * XI_S + c) = v;
    }
    // ---- stage dense features (coalesced) ----
    for (int i = t; i < TB * UFEAT; i += THREADS)
        sXU[(i / UFEAT) * XU_S + EMB + i % UFEAT] = user_feat[s0 * UFEAT + i];
    for (int i = t; i < TB * IFEAT; i += THREADS)
        sXI[(i / IFEAT) * XI_S + EMB + i % IFEAT] = item_feat[s0 * IFEAT + i];
    __syncthreads();

    const int wave = __builtin_amdgcn_readfirstlane(t >> 6);  // uniform -> scalar W loads
    const int lane = t & 63;

    // ---- layers 1&2: waves 0-7 user (8 outputs each), waves 8-15 item ----
    float acc[8];
    if (wave < 8) layer_tiled8<KXU, 5>(sXU + lane * XU_S, wave * 8,       W_uf, b_uf, acc);
    else          layer_tiled8<KXI, 6>(sXI + lane * XI_S, (wave - 8) * 8, W_if, b_if, acc);
    __syncthreads();                       // all X reads done -> safe to overwrite with H

    {
        float* Hrow = smem + lane * H_S;
        const int hoff = (wave < 8) ? wave * 8 : EMB + (wave - 8) * 8;   // mult of 8 -> aligned
        float4 h0 = {fmaxf(acc[0], 0.f), fmaxf(acc[1], 0.f), fmaxf(acc[2], 0.f), fmaxf(acc[3], 0.f)};
        float4 h1 = {fmaxf(acc[4], 0.f), fmaxf(acc[5], 0.f), fmaxf(acc[6], 0.f), fmaxf(acc[7], 0.f)};
        *reinterpret_cast<float4*>(Hrow + hoff)     = h0;
        *reinterpret_cast<float4*>(Hrow + hoff + 4) = h1;
    }
    __syncthreads();

    // ---- layer 3 (+ fused 256->1 head): each wave owns 16 hidden outputs,
    // k-tiled by 16 with h in VGPRs and contiguous W1 row runs ----
    {
        const int o0 = wave * 16;
        float a3[16];
        #pragma unroll
        for (int j = 0; j < 16; ++j) a3[j] = b1[o0 + j];
        const float* h = smem + lane * H_S;
        #pragma unroll 2
        for (int tt = 0; tt < 8; ++tt) {
            const int k0 = tt * 16;
            float hv[16];
            #pragma unroll
            for (int q = 0; q < 4; ++q) {
                const float4 v = *reinterpret_cast<const float4*>(h + k0 + q * 4);
                hv[q * 4 + 0] = v.x; hv[q * 4 + 1] = v.y;
                hv[q * 4 + 2] = v.z; hv[q * 4 + 3] = v.w;
            }
            #pragma unroll
            for (int j = 0; j < 16; ++j) {
                const float* Wr = W1 + (o0 + j) * HW + k0;   // contiguous, uniform
                #pragma unroll
                for (int kk = 0; kk < 16; ++kk)
                    a3[j] = fmaf(hv[kk], Wr[kk], a3[j]);
            }
        }
        float op = 0.f;
        #pragma unroll
        for (int j = 0; j < 16; ++j)
            op = fmaf(fmaxf(a3[j], 0.f), W2[o0 + j], op);
        sOut[wave][lane] = op;
    }
    __syncthreads();

    // ---- reduce 16 wave-partials per sample ----
    if (t < TB) {
        float r = b2[0];
        #pragma unroll
        for (int w = 0; w < NWAVE; ++w) r += sOut[w][t];
        out[s0 + t] = r;
    }
}

extern "C" void kernel_launch(void* const* d_in, const int* in_sizes, int n_in,
                              void* d_out, int out_size, void* d_ws, size_t ws_size,
                              hipStream_t stream) {
    const int*   user_id   = (const int*)  d_in[0];
    const int*   item_id   = (const int*)  d_in[1];
    const float* user_feat = (const float*)d_in[2];
    const float* item_feat = (const float*)d_in[3];
    const float* user_emb  = (const float*)d_in[4];
    const float* item_emb  = (const float*)d_in[5];
    const float* W_uf      = (const float*)d_in[6];
    const float* b_uf      = (const float*)d_in[7];
    const float* W_if      = (const float*)d_in[8];
    const float* b_if      = (const float*)d_in[9];
    const float* W1        = (const float*)d_in[10];
    const float* b1        = (const float*)d_in[11];
    const float* W2        = (const float*)d_in[12];
    const float* b2        = (const float*)d_in[13];
    float* out = (float*)d_out;

    const int blocks = 16384 / TB;   // 256 = one block per CU
    rec_fused<<<blocks, THREADS, 0, stream>>>(
        user_id, item_id, user_feat, item_feat, user_emb, item_emb,
        W_uf, b_uf, W_if, b_if, W1, b1, W2, b2, out);
}

// Round 8
// 408.638 us; speedup vs baseline: 1.0524x; 1.0524x over previous
//
#include <hip/hip_runtime.h>

#define TB      64      // samples per block (== wavefront; lane = sample)
#define THREADS 1024    // 16 waves -> 4 waves/SIMD
#define NWAVE   16
#define EMB     64
#define UFEAT   21
#define IFEAT   39
#define KXU     85      // EMB + UFEAT
#define KXI     103     // EMB + IFEAT
#define HW      128     // 2*EMB
// odd row strides -> lane*stride hits all 32 banks; column-broadcast reads are 2-way (free)
#define XU_S    89
#define XI_S    105
#define H_S     129

template<int K>
__device__ __forceinline__ void layer8(const float* __restrict__ x, int o0,
                                       const float* __restrict__ W,
                                       const float* __restrict__ b,
                                       float acc[8])
{
    // init: bias + raw-embedding residual (x[0..63] = raw embedding)
    #pragma unroll
    for (int j = 0; j < 8; ++j) acc[j] = b[o0 + j] + x[o0 + j];
    // dot over relu(concat(emb, feat)); W addresses are wave-uniform -> s_load
    #pragma unroll 4
    for (int k = 0; k < K; ++k) {
        const float a = fmaxf(x[k], 0.f);
        #pragma unroll
        for (int j = 0; j < 8; ++j)
            acc[j] = fmaf(a, W[(o0 + j) * K + k], acc[j]);
    }
}

__global__ __launch_bounds__(THREADS, 4)
void rec_fused(const int*   __restrict__ user_id,  const int*   __restrict__ item_id,
               const float* __restrict__ user_feat, const float* __restrict__ item_feat,
               const float* __restrict__ user_emb,  const float* __restrict__ item_emb,
               const float* __restrict__ W_uf, const float* __restrict__ b_uf,
               const float* __restrict__ W_if, const float* __restrict__ b_if,
               const float* __restrict__ W1,  const float* __restrict__ b1,
               const float* __restrict__ W2,  const float* __restrict__ b2,
               float* __restrict__ out)
{
    // X staging and H (hidden) alias the same LDS: H (64*129 floats) fits inside
    // X (64*(89+105) floats); H is written only after all X reads complete.
    __shared__ float smem[TB * XU_S + TB * XI_S];   // 49664 B
    __shared__ float sOut[NWAVE][TB];               // 4096 B  -> 52.5 KB total

    const int t  = threadIdx.x;
    const int s0 = blockIdx.x * TB;
    float* sXU = smem;                 // row stride XU_S
    float* sXI = smem + TB * XU_S;     // row stride XI_S

    // ---- stage embeddings: 1024 threads, one float4 per table each; user+item
    // issued back-to-back so their HBM latencies overlap ----
    {
        const int r = t >> 4, c = (t & 15) << 2;
        const int uid = user_id[s0 + r];
        const int iid = item_id[s0 + r];
        const float4 u = *reinterpret_cast<const float4*>(user_emb + uid * EMB + c);
        const float4 v = *reinterpret_cast<const float4*>(item_emb + iid * EMB + c);
        float* pu = sXU + r * XU_S + c;
        pu[0] = u.x; pu[1] = u.y; pu[2] = u.z; pu[3] = u.w;
        float* pi = sXI + r * XI_S + c;
        pi[0] = v.x; pi[1] = v.y; pi[2] = v.z; pi[3] = v.w;
    }
    // ---- stage dense features (coalesced) ----
    for (int i = t; i < TB * UFEAT; i += THREADS)
        sXU[(i / UFEAT) * XU_S + EMB + i % UFEAT] = user_feat[s0 * UFEAT + i];
    for (int i = t; i < TB * IFEAT; i += THREADS)
        sXI[(i / IFEAT) * XI_S + EMB + i % IFEAT] = item_feat[s0 * IFEAT + i];
    __syncthreads();

    const int wave = __builtin_amdgcn_readfirstlane(t >> 6);  // uniform -> scalar weight loads
    const int lane = t & 63;

    // ---- layers 1&2: waves 0-7 user (8 outputs each), waves 8-15 item ----
    float acc[8];
    if (wave < 8) layer8<KXU>(sXU + lane * XU_S, wave * 8,       W_uf, b_uf, acc);
    else          layer8<KXI>(sXI + lane * XI_S, (wave - 8) * 8, W_if, b_if, acc);
    __syncthreads();                       // all X reads done -> safe to overwrite with H

    {
        float* Hrow = smem + lane * H_S;
        const int hoff = (wave < 8) ? wave * 8 : EMB + (wave - 8) * 8;
        #pragma unroll
        for (int j = 0; j < 8; ++j) Hrow[hoff + j] = fmaxf(acc[j], 0.f);
    }
    __syncthreads();

    // ---- layer 3 (+ fused 256->1 head): each wave owns 16 hidden outputs ----
    {
        const int o0 = wave * 16;
        float a3[16];
        #pragma unroll
        for (int j = 0; j < 16; ++j) a3[j] = b1[o0 + j];
        const float* h = smem + lane * H_S;
        #pragma unroll 4
        for (int k = 0; k < HW; ++k) {
            const float a = h[k];
            #pragma unroll
            for (int j = 0; j < 16; ++j)
                a3[j] = fmaf(a, W1[(o0 + j) * HW + k], a3[j]);
        }
        float op = 0.f;
        #pragma unroll
        for (int j = 0; j < 16; ++j)
            op = fmaf(fmaxf(a3[j], 0.f), W2[o0 + j], op);
        sOut[wave][lane] = op;
    }
    __syncthreads();

    // ---- reduce 16 wave-partials per sample ----
    if (t < TB) {
        float r = b2[0];
        #pragma unroll
        for (int w = 0; w < NWAVE; ++w) r += sOut[w][t];
        out[s0 + t] = r;
    }
}

extern "C" void kernel_launch(void* const* d_in, const int* in_sizes, int n_in,
                              void* d_out, int out_size, void* d_ws, size_t ws_size,
                              hipStream_t stream) {
    const int*   user_id   = (const int*)  d_in[0];
    const int*   item_id   = (const int*)  d_in[1];
    const float* user_feat = (const float*)d_in[2];
    const float* item_feat = (const float*)d_in[3];
    const float* user_emb  = (const float*)d_in[4];
    const float* item_emb  = (const float*)d_in[5];
    const float* W_uf      = (const float*)d_in[6];
    const float* b_uf      = (const float*)d_in[7];
    const float* W_if      = (const float*)d_in[8];
    const float* b_if      = (const float*)d_in[9];
    const float* W1        = (const float*)d_in[10];
    const float* b1        = (const float*)d_in[11];
    const float* W2        = (const float*)d_in[12];
    const float* b2        = (const float*)d_in[13];
    float* out = (float*)d_out;

    const int blocks = 16384 / TB;   // 256 = one block per CU
    rec_fused<<<blocks, THREADS, 0, stream>>>(
        user_id, item_id, user_feat, item_feat, user_emb, item_emb,
        W_uf, b_uf, W_if, b_if, W1, b1, W2, b2, out);
}